// Round 14
// baseline (599.325 us; speedup 1.0000x reference)
//
#include <hip/hip_runtime.h>
#include <hip/hip_bf16.h>

// Bidirectional ConvLSTM, B=8 T=16 C=3 H=W=32 hid=64 K=7 ('SAME').
// Round 16: REVERT to R14-verified structure (587.3us; R15's split epilogue
// regressed -11us -> extra barrier + reload cost > halved epilogue) plus
// the two mechanism-independent scraps from R15:
//   1. s==15 dead-write skip (c, hp_w never read after final step; bit-exact)
//   2. dtype probe inlined into prep_weights (one fewer serial launch);
//      block 0 writes the flag for lstm_step.
// Kernel body otherwise byte-identical to Round-14 bench (passed, 587.3us):
//   single-shot 64KB exchange (3 barriers), memsetAsync zero, s==0 fast
//   path, coalesced XB, dir-in-LSB grid, setprio, 2-deep pipe, kg0 epilogue.
//
// Workspace (BYTE offsets), total 13,862,916 B:
//   hp0 : padded h ping, bf16 [dir][b][row38][col40][ic64] @ 0        (3,112,960)
//   hp1 : padded h pong                                    @ 3112960  (3,112,960)
//   c   : cell,  fp32 [dir][b][y32][x32][hid64]            @ 6225920  (4,194,304)
//   wall: bf16 [dir][ks105][oc256][k32]                    @ 10420224 (3,440,640)
//   bias: fp32 [dir][256]                                  @ 13860864 (2,048)
//   flag: int (1 = fp32 inputs)                            @ 13862912 (4)

#define HP0_B  0
#define HP1_B  3112960
#define C_B    6225920
#define WALL_B 10420224
#define BIAS_B 13860864
#define FLAG_B 13862912

using short8 = __attribute__((ext_vector_type(8))) short;
using f32x4  = __attribute__((ext_vector_type(4))) float;

__device__ __forceinline__ float sigm(float x) { return 1.0f / (1.0f + __expf(-x)); }
__device__ __forceinline__ float tanh_f(float x) {
    x = fminf(fmaxf(x, -30.0f), 30.0f);
    float e = __expf(2.0f * x);
    return (e - 1.0f) / (e + 1.0f);
}

// ---- weights -> wall[d][ks][oc][k32] bf16 + bias; dtype probe inlined ----
__global__ void prep_weights(const void* __restrict__ whhf, const void* __restrict__ whhb,
                             const void* __restrict__ wihf, const void* __restrict__ wihb,
                             const void* __restrict__ bf, const void* __restrict__ bb,
                             short* __restrict__ wall, float* __restrict__ bias_r,
                             const unsigned int* __restrict__ xw,
                             int* __restrict__ flag_w) {
    __shared__ int sflag;
    // dtype probe (verified round-2 logic, relocated): wave 0 samples x
    if (threadIdx.x < 64) {
        int lane = threadIdx.x;
        int cnt = 0;
        for (int i = 0; i < 4; ++i) {
            unsigned int w = xw[lane * 4 + i];
            unsigned int e = (w >> 7) & 0xFFu;
            cnt += (e >= 0xC0u) ? 1 : 0;
        }
#pragma unroll
        for (int off = 32; off > 0; off >>= 1) cnt += __shfl_down(cnt, off, 64);
        if (lane == 0) sflag = (cnt > 16) ? 1 : 0;
    }
    __syncthreads();
    const int fp32 = sflag;
    if (blockIdx.x == 0 && threadIdx.x == 0) *flag_w = fp32;

    int n = blockIdx.x * blockDim.x + threadIdx.x;
    if (n < 1720320) {
        int icl = n & 31;
        int oc = (n >> 5) & 255;
        int ks = (n >> 13) % 105;
        int d = n / 860160;
        const void* hh = d ? whhb : whhf;
        const void* ih = d ? wihb : wihf;
        float v = 0.0f;
        if (ks < 98) {
            int ky = ks / 14, rr = ks % 14, kc = rr / 7, kx = rr % 7;
            int si = ((oc * 64 + kc * 32 + icl) * 7 + ky) * 7 + kx;
            v = fp32 ? ((const float*)hh)[si] : __bfloat162float(((const __hip_bfloat16*)hh)[si]);
        } else {
            int kx = ks - 98, ky = icl >> 2, ic = icl & 3;
            if (ic < 3 && ky < 7) {
                int si = ((oc * 3 + ic) * 7 + ky) * 7 + kx;
                v = fp32 ? ((const float*)ih)[si] : __bfloat162float(((const __hip_bfloat16*)ih)[si]);
            }
        }
        __hip_bfloat16 hv = __float2bfloat16(v);
        wall[n] = *(short*)&hv;
        return;
    }
    n -= 1720320;
    if (n < 512) {
        const void* src = (n >= 256) ? bb : bf;
        int j = n & 255;
        bias_r[n] = fp32 ? ((const float*)src)[j] : __bfloat162float(((const __hip_bfloat16*)src)[j]);
    }
}

// ---- MFMA step kernel (64 KB dynamic LDS, single-shot exchange) ----------
// grid 256 blocks 1D (bid: dir = bit0, b = bits1-3, ygrp = bits4-7), 512 thr
// = 8 waves (4 M-split x 2 K-split).
// LDS (65,536 B dynamic), overlaid:
//   K-loop  : h tile [8][40][72] + XB [2][40][40] = 26240 shorts (52,480 B)
//   exchange: kg=1 full partial acc, fp32 [wm4][slot16][q4][li16][4] (65,536 B)
__global__ __launch_bounds__(512, 2)
void lstm_step(const void* __restrict__ xin,
               const short* __restrict__ wall,
               const float* __restrict__ bias_r,
               const unsigned short* __restrict__ hp_r,
               unsigned short* __restrict__ hp_w,
               float* __restrict__ c,
               void* __restrict__ out,
               const int* __restrict__ flag, int s) {
    extern __shared__ short lds[];
    const int bid = blockIdx.x;
    const int dir = bid & 1;          // dir in LSB: XCD=bid%8 -> one dir per XCD
    const int b = (bid >> 1) & 7;
    const int ygrp = bid >> 4;
    const int t = dir ? (15 - s) : s;
    const int y0 = ygrp * 2;
    const int tid = threadIdx.x;
    const int wv = tid >> 6;          // 0..7
    const int kg = wv >> 2;           // K-group
    const int wm = wv & 3;            // M-split role
    const int l = tid & 63;
    const int q = l >> 4;
    const int li = l & 15;
    const int fp32 = *flag;
    const int db = dir * 8 + b;

    // stage h rows y0..y0+7 into padded LDS -- skipped at s==0 (h==0)
    if (s != 0) {
        const uint4* src = (const uint4*)(hp_r + (size_t)(db * 38 + y0) * 40 * 64);
        for (int i = tid; i < 2560; i += 512) {
            int ic8 = i & 7, col = (i >> 3) % 40, row = i / 320;
            uint4 v = src[i];
            *(uint4*)&lds[(row * 40 + col) * 72 + ic8 * 8] = v;
        }
    }
    // build XB[r][cc][k=ky*4+ic] -- cc-inner index map (coalesced, R10 win)
    for (int i = tid; i < 3200; i += 512) {
        int cc = i % 40;
        int r  = (i / 40) & 1;
        int k  = i / 80;              // 0..39
        float v = 0.0f;
        if (k < 28) {
            int ky = k >> 2, ic = k & 3;
            int yin = y0 + r + ky - 3, cin = cc - 3;
            if (ic < 3 && yin >= 0 && yin < 32 && cin >= 0 && cin < 32) {
                size_t gi = (size_t)((b * 16 + t) * 3 + ic) * 1024 + yin * 32 + cin;
                v = fp32 ? ((const float*)xin)[gi]
                         : __bfloat162float(((const __hip_bfloat16*)xin)[gi]);
            }
        }
        __hip_bfloat16 hb = __float2bfloat16(v);
        lds[23040 + (r * 40 + cc) * 40 + k] = *(short*)&hb;
    }
    __syncthreads();

    // acc init: kg=0 carries the bias, kg=1 starts at zero (partials)
    f32x4 acc[4][4];
    if (kg == 0) {
        const float* bp = bias_r + dir * 256 + wm * 16 + q * 4;
#pragma unroll
        for (int g = 0; g < 4; ++g) {
            f32x4 bv = *(const f32x4*)(bp + g * 64);
#pragma unroll
            for (int nt = 0; nt < 4; ++nt) acc[g][nt] = bv;
        }
    } else {
        f32x4 z = {0.0f, 0.0f, 0.0f, 0.0f};
#pragma unroll
        for (int g = 0; g < 4; ++g)
#pragma unroll
            for (int nt = 0; nt < 4; ++nt) acc[g][nt] = z;
    }

    // lane bases
    const short* wbase = wall + (size_t)dir * 860160 + ((wm * 16 + li) * 32 + q * 8);
    int bh[4], bx[4];
#pragma unroll
    for (int nt = 0; nt < 4; ++nt) {
        int rt = nt >> 1, ct = nt & 1;
        bh[nt] = (rt * 40 + ct * 16 + li) * 72 + q * 8;
        bx[nt] = 23040 + (rt * 40 + ct * 16 + li) * 40 + q * 8;
    }

    auto loadA = [&](short8* A, int ks) {
        const short* p = wbase + (size_t)ks * 8192;
#pragma unroll
        for (int g = 0; g < 4; ++g) A[g] = *(const short8*)(p + g * 2048);
    };
    auto loadB = [&](short8* B, int ks) {
        if (ks < 98) {
            int ky = ks / 14, rr = ks % 14;
            int uoff = ky * 2880 + (rr % 7) * 72 + (rr / 7) * 32;
#pragma unroll
            for (int nt = 0; nt < 4; ++nt) B[nt] = *(const short8*)&lds[bh[nt] + uoff];
        } else {
            int uoff = (ks - 98) * 40;
#pragma unroll
            for (int nt = 0; nt < 4; ++nt) B[nt] = *(const short8*)&lds[bx[nt] + uoff];
        }
    };
    auto mfma16 = [&](short8* A, short8* B) {
        __builtin_amdgcn_s_setprio(1);      // T5
#pragma unroll
        for (int g = 0; g < 4; ++g)
#pragma unroll
            for (int nt = 0; nt < 4; ++nt)
                acc[g][nt] = __builtin_amdgcn_mfma_f32_16x16x32_bf16(A[g], B[nt], acc[g][nt], 0, 0, 0);
        __builtin_amdgcn_s_setprio(0);
    };

    // K-loop ranges: s==0 -> h==0 exactly, only x-conv ks [98,105) needed.
    const int ks_begin = (s == 0) ? (kg ? 101 : 98) : (kg ? 52 : 0);
    const int ks_end   = (s == 0) ? (kg ? 105 : 101) : (kg ? 105 : 52);
    short8 A0[4], A1[4], B0[4], B1[4];
    loadA(A0, ks_begin); loadB(B0, ks_begin);
    int ks = ks_begin;
#pragma unroll 1
    for (; ks + 1 < ks_end; ks += 2) {
        loadA(A1, ks + 1); loadB(B1, ks + 1);
        mfma16(A0, B0);
        int kn = (ks + 2 < ks_end) ? ks + 2 : ks; // clamp (redundant reload on last iter)
        loadA(A0, kn); loadB(B0, kn);
        mfma16(A1, B1);
    }
    if (ks < ks_end) mfma16(A0, B0); // odd-count tail

    // ---- combine partials: single-shot (64 KB exchange region) -----------
    // Fully unrolled, CONSTANT acc indices only (rule #20).
    __syncthreads();           // all waves done with h-tile/XB reads
    {
        float* exch = (float*)lds;
        float* xp = exch + wm * 4096 + q * 64 + li * 4;
        if (kg == 1) {
#pragma unroll
            for (int g = 0; g < 4; ++g)
#pragma unroll
                for (int nt = 0; nt < 4; ++nt)
                    *(f32x4*)(xp + (g * 4 + nt) * 256) = acc[g][nt];
        }
        __syncthreads();
        if (kg == 0) {
#pragma unroll
            for (int g = 0; g < 4; ++g)
#pragma unroll
                for (int nt = 0; nt < 4; ++nt)
                    acc[g][nt] += *(const f32x4*)(xp + (g * 4 + nt) * 256);
        }
    }
    if (kg == 1) return;       // no barriers past this point

    // epilogue (kg=0 only; all 4 gates present in-wave)
    const int hid0 = wm * 16 + q * 4;
#pragma unroll
    for (int nt = 0; nt < 4; ++nt) {
        int y = y0 + (nt >> 1);
        int px = (nt & 1) * 16 + li;
        float* cp = c + (size_t)(db * 1024 + y * 32 + px) * 64 + hid0;
        f32x4 cold;
        if (s == 0) {          // c == 0 at s=0: skip the cold read (bit-exact)
            cold = (f32x4){0.0f, 0.0f, 0.0f, 0.0f};
        } else {
            cold = *(const f32x4*)cp;
        }
        f32x4 hv;
#pragma unroll
        for (int r = 0; r < 4; ++r) {
            float iv = sigm(acc[0][nt][r]);
            float fv = sigm(acc[1][nt][r]);
            float gv = tanh_f(acc[2][nt][r]);
            float ov = sigm(acc[3][nt][r]);
            float cn = fv * cold[r] + iv * gv;
            cold[r] = cn;
            hv[r] = ov * tanh_f(cn);
        }
        if (s != 15) {         // c and hp_w are dead after the final step
            *(f32x4*)cp = cold;
            ushort4 hu;
            __hip_bfloat16 t0 = __float2bfloat16(hv[0]); hu.x = *(unsigned short*)&t0;
            __hip_bfloat16 t1 = __float2bfloat16(hv[1]); hu.y = *(unsigned short*)&t1;
            __hip_bfloat16 t2 = __float2bfloat16(hv[2]); hu.z = *(unsigned short*)&t2;
            __hip_bfloat16 t3 = __float2bfloat16(hv[3]); hu.w = *(unsigned short*)&t3;
            *(ushort4*)(hp_w + (size_t)((db * 38 + y + 3) * 40 + px + 3) * 64 + hid0) = hu;
        }

        size_t ob = (size_t)((b * 16 + t) * 128 + dir * 64 + hid0) * 1024 + y * 32 + px;
        if (fp32) {
            float* op = (float*)out;
#pragma unroll
            for (int r = 0; r < 4; ++r) op[ob + (size_t)r * 1024] = hv[r];
        } else {
            __hip_bfloat16* op = (__hip_bfloat16*)out;
#pragma unroll
            for (int r = 0; r < 4; ++r) op[ob + (size_t)r * 1024] = __float2bfloat16(hv[r]);
        }
    }
}

// ---- FALLBACK: R13-verified static-LDS kernel (592.4 us, passed) ---------
__global__ __launch_bounds__(512, 2)
void lstm_step_fb(const void* __restrict__ xin,
                  const short* __restrict__ wall,
                  const float* __restrict__ bias_r,
                  const unsigned short* __restrict__ hp_r,
                  unsigned short* __restrict__ hp_w,
                  float* __restrict__ c,
                  void* __restrict__ out,
                  const int* __restrict__ flag, int s) {
    const int bid = blockIdx.x;
    const int dir = bid & 1;
    const int b = (bid >> 1) & 7;
    const int ygrp = bid >> 4;
    const int t = dir ? (15 - s) : s;
    const int y0 = ygrp * 2;
    const int tid = threadIdx.x;
    const int wv = tid >> 6;
    const int kg = wv >> 2;
    const int wm = wv & 3;
    const int l = tid & 63;
    const int q = l >> 4;
    const int li = l & 15;
    const int fp32 = *flag;
    const int db = dir * 8 + b;

    __shared__ __align__(16) short lds[26240];

    if (s != 0) {
        const uint4* src = (const uint4*)(hp_r + (size_t)(db * 38 + y0) * 40 * 64);
        for (int i = tid; i < 2560; i += 512) {
            int ic8 = i & 7, col = (i >> 3) % 40, row = i / 320;
            uint4 v = src[i];
            *(uint4*)&lds[(row * 40 + col) * 72 + ic8 * 8] = v;
        }
    }
    for (int i = tid; i < 3200; i += 512) {
        int cc = i % 40;
        int r  = (i / 40) & 1;
        int k  = i / 80;
        float v = 0.0f;
        if (k < 28) {
            int ky = k >> 2, ic = k & 3;
            int yin = y0 + r + ky - 3, cin = cc - 3;
            if (ic < 3 && yin >= 0 && yin < 32 && cin >= 0 && cin < 32) {
                size_t gi = (size_t)((b * 16 + t) * 3 + ic) * 1024 + yin * 32 + cin;
                v = fp32 ? ((const float*)xin)[gi]
                         : __bfloat162float(((const __hip_bfloat16*)xin)[gi]);
            }
        }
        __hip_bfloat16 hb = __float2bfloat16(v);
        lds[23040 + (r * 40 + cc) * 40 + k] = *(short*)&hb;
    }
    __syncthreads();

    f32x4 acc[4][4];
    if (kg == 0) {
        const float* bp = bias_r + dir * 256 + wm * 16 + q * 4;
#pragma unroll
        for (int g = 0; g < 4; ++g) {
            f32x4 bv = *(const f32x4*)(bp + g * 64);
#pragma unroll
            for (int nt = 0; nt < 4; ++nt) acc[g][nt] = bv;
        }
    } else {
        f32x4 z = {0.0f, 0.0f, 0.0f, 0.0f};
#pragma unroll
        for (int g = 0; g < 4; ++g)
#pragma unroll
            for (int nt = 0; nt < 4; ++nt) acc[g][nt] = z;
    }

    const short* wbase = wall + (size_t)dir * 860160 + ((wm * 16 + li) * 32 + q * 8);
    int bh[4], bx[4];
#pragma unroll
    for (int nt = 0; nt < 4; ++nt) {
        int rt = nt >> 1, ct = nt & 1;
        bh[nt] = (rt * 40 + ct * 16 + li) * 72 + q * 8;
        bx[nt] = 23040 + (rt * 40 + ct * 16 + li) * 40 + q * 8;
    }

    auto loadA = [&](short8* A, int ks) {
        const short* p = wbase + (size_t)ks * 8192;
#pragma unroll
        for (int g = 0; g < 4; ++g) A[g] = *(const short8*)(p + g * 2048);
    };
    auto loadB = [&](short8* B, int ks) {
        if (ks < 98) {
            int ky = ks / 14, rr = ks % 14;
            int uoff = ky * 2880 + (rr % 7) * 72 + (rr / 7) * 32;
#pragma unroll
            for (int nt = 0; nt < 4; ++nt) B[nt] = *(const short8*)&lds[bh[nt] + uoff];
        } else {
            int uoff = (ks - 98) * 40;
#pragma unroll
            for (int nt = 0; nt < 4; ++nt) B[nt] = *(const short8*)&lds[bx[nt] + uoff];
        }
    };
    auto mfma16 = [&](short8* A, short8* B) {
        __builtin_amdgcn_s_setprio(1);
#pragma unroll
        for (int g = 0; g < 4; ++g)
#pragma unroll
            for (int nt = 0; nt < 4; ++nt)
                acc[g][nt] = __builtin_amdgcn_mfma_f32_16x16x32_bf16(A[g], B[nt], acc[g][nt], 0, 0, 0);
        __builtin_amdgcn_s_setprio(0);
    };

    const int ks_begin = (s == 0) ? (kg ? 101 : 98) : (kg ? 52 : 0);
    const int ks_end   = (s == 0) ? (kg ? 105 : 101) : (kg ? 105 : 52);
    short8 A0[4], A1[4], B0[4], B1[4];
    loadA(A0, ks_begin); loadB(B0, ks_begin);
    int ks = ks_begin;
#pragma unroll 1
    for (; ks + 1 < ks_end; ks += 2) {
        loadA(A1, ks + 1); loadB(B1, ks + 1);
        mfma16(A0, B0);
        int kn = (ks + 2 < ks_end) ? ks + 2 : ks;
        loadA(A0, kn); loadB(B0, kn);
        mfma16(A1, B1);
    }
    if (ks < ks_end) mfma16(A0, B0);

    __syncthreads();
    {
        float* exch = (float*)lds;
        float* xp = exch + wm * 2048 + q * 64 + li * 4;
        if (kg == 1) {
#pragma unroll
            for (int g = 0; g < 2; ++g)
#pragma unroll
                for (int nt = 0; nt < 4; ++nt)
                    *(f32x4*)(xp + (g * 4 + nt) * 256) = acc[g][nt];
        }
        __syncthreads();
        if (kg == 0) {
#pragma unroll
            for (int g = 0; g < 2; ++g)
#pragma unroll
                for (int nt = 0; nt < 4; ++nt)
                    acc[g][nt] += *(const f32x4*)(xp + (g * 4 + nt) * 256);
        }
        __syncthreads();
        if (kg == 1) {
#pragma unroll
            for (int g = 0; g < 2; ++g)
#pragma unroll
                for (int nt = 0; nt < 4; ++nt)
                    *(f32x4*)(xp + (g * 4 + nt) * 256) = acc[2 + g][nt];
        }
        __syncthreads();
        if (kg == 0) {
#pragma unroll
            for (int g = 0; g < 2; ++g)
#pragma unroll
                for (int nt = 0; nt < 4; ++nt)
                    acc[2 + g][nt] += *(const f32x4*)(xp + (g * 4 + nt) * 256);
        }
    }
    if (kg == 1) return;

    const int hid0 = wm * 16 + q * 4;
#pragma unroll
    for (int nt = 0; nt < 4; ++nt) {
        int y = y0 + (nt >> 1);
        int px = (nt & 1) * 16 + li;
        float* cp = c + (size_t)(db * 1024 + y * 32 + px) * 64 + hid0;
        f32x4 cold = *(const f32x4*)cp;
        f32x4 hv;
#pragma unroll
        for (int r = 0; r < 4; ++r) {
            float iv = sigm(acc[0][nt][r]);
            float fv = sigm(acc[1][nt][r]);
            float gv = tanh_f(acc[2][nt][r]);
            float ov = sigm(acc[3][nt][r]);
            float cn = fv * cold[r] + iv * gv;
            cold[r] = cn;
            hv[r] = ov * tanh_f(cn);
        }
        *(f32x4*)cp = cold;

        ushort4 hu;
        {
            __hip_bfloat16 t0 = __float2bfloat16(hv[0]); hu.x = *(unsigned short*)&t0;
            __hip_bfloat16 t1 = __float2bfloat16(hv[1]); hu.y = *(unsigned short*)&t1;
            __hip_bfloat16 t2 = __float2bfloat16(hv[2]); hu.z = *(unsigned short*)&t2;
            __hip_bfloat16 t3 = __float2bfloat16(hv[3]); hu.w = *(unsigned short*)&t3;
        }
        *(ushort4*)(hp_w + (size_t)((db * 38 + y + 3) * 40 + px + 3) * 64 + hid0) = hu;

        size_t ob = (size_t)((b * 16 + t) * 128 + dir * 64 + hid0) * 1024 + y * 32 + px;
        if (fp32) {
            float* op = (float*)out;
#pragma unroll
            for (int r = 0; r < 4; ++r) op[ob + (size_t)r * 1024] = hv[r];
        } else {
            __hip_bfloat16* op = (__hip_bfloat16*)out;
#pragma unroll
            for (int r = 0; r < 4; ++r) op[ob + (size_t)r * 1024] = __float2bfloat16(hv[r]);
        }
    }
}

extern "C" void kernel_launch(void* const* d_in, const int* in_sizes, int n_in,
                              void* d_out, int out_size, void* d_ws, size_t ws_size,
                              hipStream_t stream) {
    char* wsb = (char*)d_ws;
    unsigned short* hp0 = (unsigned short*)(wsb + HP0_B);
    unsigned short* hp1 = (unsigned short*)(wsb + HP1_B);
    float* c = (float*)(wsb + C_B);
    short* wall = (short*)(wsb + WALL_B);
    float* bias_r = (float*)(wsb + BIAS_B);
    int* flag = (int*)(wsb + FLAG_B);

    static int big_lds_ok = -1;
    if (big_lds_ok < 0) {
        hipError_t e = hipFuncSetAttribute((const void*)lstm_step,
                                           hipFuncAttributeMaxDynamicSharedMemorySize,
                                           65536);
        big_lds_ok = (e == hipSuccess) ? 1 : 0;
    }

    // inputs: 0=x 1=w_ih_f 2=w_hh_f 3=b_f 4=w_ih_b 5=w_hh_b 6=b_b
    hipMemsetAsync(d_ws, 0, 10420224, stream);   // hp0+hp1+c (capture-safe)
    prep_weights<<<6722, 256, 0, stream>>>(d_in[2], d_in[5], d_in[1], d_in[4],
                                           d_in[3], d_in[6], wall, bias_r,
                                           (const unsigned int*)d_in[0], flag);

    if (big_lds_ok) {
        for (int s = 0; s < 16; ++s) {
            unsigned short* hr = (s & 1) ? hp1 : hp0;
            unsigned short* hw = (s & 1) ? hp0 : hp1;
            lstm_step<<<dim3(256), 512, 65536, stream>>>(d_in[0], wall, bias_r,
                                                         hr, hw, c, d_out, flag, s);
        }
    } else {
        for (int s = 0; s < 16; ++s) {
            unsigned short* hr = (s & 1) ? hp1 : hp0;
            unsigned short* hw = (s & 1) ? hp0 : hp1;
            lstm_step_fb<<<dim3(256), 512, 0, stream>>>(d_in[0], wall, bias_r,
                                                        hr, hw, c, d_out, flag, s);
        }
    }
}

// Round 15
// 591.261 us; speedup vs baseline: 1.0136x; 1.0136x over previous
//
#include <hip/hip_runtime.h>
#include <hip/hip_bf16.h>

// Bidirectional ConvLSTM, B=8 T=16 C=3 H=W=32 hid=64 K=7 ('SAME').
// Round 17 = EXACT RESTORE of the Round-12-benched kernel (587.3us, best
// measured). R13's split epilogue (-11us) and R14's s15-skip+inlined-probe
// (-12us) both regressed vs this configuration; reverting to the verified
// optimum. Structure:
//   - 16 launches; 8 waves = 4 M-split x 2 K-split; 2-deep pipe
//   - dir-in-LSB grid (one dir per XCD); setprio around MFMA (T5)
//   - coalesced cc-inner XB build (R10 win, +27us)
//   - s==0 fast path: K-range [98,105) only, no h-stage, no c-read (+25us)
//   - single-shot 64KB dynamic-LDS exchange, 3 barriers/step (+5us)
//   - memsetAsync state zero; kg0-only in-wave epilogue
//
// Workspace (BYTE offsets), total 13,862,916 B:
//   hp0 : padded h ping, bf16 [dir][b][row38][col40][ic64] @ 0        (3,112,960)
//   hp1 : padded h pong                                    @ 3112960  (3,112,960)
//   c   : cell,  fp32 [dir][b][y32][x32][hid64]            @ 6225920  (4,194,304)
//   wall: bf16 [dir][ks105][oc256][k32]                    @ 10420224 (3,440,640)
//   bias: fp32 [dir][256]                                  @ 13860864 (2,048)
//   flag: int (1 = fp32 inputs)                            @ 13862912 (4)

#define HP0_B  0
#define HP1_B  3112960
#define C_B    6225920
#define WALL_B 10420224
#define BIAS_B 13860864
#define FLAG_B 13862912

using short8 = __attribute__((ext_vector_type(8))) short;
using f32x4  = __attribute__((ext_vector_type(4))) float;

__device__ __forceinline__ float sigm(float x) { return 1.0f / (1.0f + __expf(-x)); }
__device__ __forceinline__ float tanh_f(float x) {
    x = fminf(fmaxf(x, -30.0f), 30.0f);
    float e = __expf(2.0f * x);
    return (e - 1.0f) / (e + 1.0f);
}

// ---- dtype probe (verified) ---------------------------------------------
__global__ void detect_dtype(const unsigned int* __restrict__ xw, int* __restrict__ flag) {
    int lane = threadIdx.x;
    int cnt = 0;
    for (int i = 0; i < 4; ++i) {
        unsigned int w = xw[lane * 4 + i];
        unsigned int e = (w >> 7) & 0xFFu;
        cnt += (e >= 0xC0u) ? 1 : 0;
    }
#pragma unroll
    for (int off = 32; off > 0; off >>= 1) cnt += __shfl_down(cnt, off, 64);
    if (lane == 0) *flag = (cnt > 16) ? 1 : 0;
}

// ---- weights -> wall[d][ks][oc][k32] bf16 + bias ------------------------
__global__ void prep_weights(const void* __restrict__ whhf, const void* __restrict__ whhb,
                             const void* __restrict__ wihf, const void* __restrict__ wihb,
                             const void* __restrict__ bf, const void* __restrict__ bb,
                             short* __restrict__ wall, float* __restrict__ bias_r,
                             const int* __restrict__ flag) {
    int n = blockIdx.x * blockDim.x + threadIdx.x;
    const int fp32 = *flag;
    if (n < 1720320) {
        int icl = n & 31;
        int oc = (n >> 5) & 255;
        int ks = (n >> 13) % 105;
        int d = n / 860160;
        const void* hh = d ? whhb : whhf;
        const void* ih = d ? wihb : wihf;
        float v = 0.0f;
        if (ks < 98) {
            int ky = ks / 14, rr = ks % 14, kc = rr / 7, kx = rr % 7;
            int si = ((oc * 64 + kc * 32 + icl) * 7 + ky) * 7 + kx;
            v = fp32 ? ((const float*)hh)[si] : __bfloat162float(((const __hip_bfloat16*)hh)[si]);
        } else {
            int kx = ks - 98, ky = icl >> 2, ic = icl & 3;
            if (ic < 3 && ky < 7) {
                int si = ((oc * 3 + ic) * 7 + ky) * 7 + kx;
                v = fp32 ? ((const float*)ih)[si] : __bfloat162float(((const __hip_bfloat16*)ih)[si]);
            }
        }
        __hip_bfloat16 hv = __float2bfloat16(v);
        wall[n] = *(short*)&hv;
        return;
    }
    n -= 1720320;
    if (n < 512) {
        const void* src = (n >= 256) ? bb : bf;
        int j = n & 255;
        bias_r[n] = fp32 ? ((const float*)src)[j] : __bfloat162float(((const __hip_bfloat16*)src)[j]);
    }
}

// ---- MFMA step kernel (64 KB dynamic LDS, single-shot exchange) ----------
// grid 256 blocks 1D (bid: dir = bit0, b = bits1-3, ygrp = bits4-7), 512 thr
// = 8 waves (4 M-split x 2 K-split).
// LDS (65,536 B dynamic), overlaid:
//   K-loop  : h tile [8][40][72] + XB [2][40][40] = 26240 shorts (52,480 B)
//   exchange: kg=1 full partial acc, fp32 [wm4][slot16][q4][li16][4] (65,536 B)
__global__ __launch_bounds__(512, 2)
void lstm_step(const void* __restrict__ xin,
               const short* __restrict__ wall,
               const float* __restrict__ bias_r,
               const unsigned short* __restrict__ hp_r,
               unsigned short* __restrict__ hp_w,
               float* __restrict__ c,
               void* __restrict__ out,
               const int* __restrict__ flag, int s) {
    extern __shared__ short lds[];
    const int bid = blockIdx.x;
    const int dir = bid & 1;          // dir in LSB: XCD=bid%8 -> one dir per XCD
    const int b = (bid >> 1) & 7;
    const int ygrp = bid >> 4;
    const int t = dir ? (15 - s) : s;
    const int y0 = ygrp * 2;
    const int tid = threadIdx.x;
    const int wv = tid >> 6;          // 0..7
    const int kg = wv >> 2;           // K-group
    const int wm = wv & 3;            // M-split role
    const int l = tid & 63;
    const int q = l >> 4;
    const int li = l & 15;
    const int fp32 = *flag;
    const int db = dir * 8 + b;

    // stage h rows y0..y0+7 into padded LDS -- skipped at s==0 (h==0)
    if (s != 0) {
        const uint4* src = (const uint4*)(hp_r + (size_t)(db * 38 + y0) * 40 * 64);
        for (int i = tid; i < 2560; i += 512) {
            int ic8 = i & 7, col = (i >> 3) % 40, row = i / 320;
            uint4 v = src[i];
            *(uint4*)&lds[(row * 40 + col) * 72 + ic8 * 8] = v;
        }
    }
    // build XB[r][cc][k=ky*4+ic] -- cc-inner index map (coalesced, R10 win)
    for (int i = tid; i < 3200; i += 512) {
        int cc = i % 40;
        int r  = (i / 40) & 1;
        int k  = i / 80;              // 0..39
        float v = 0.0f;
        if (k < 28) {
            int ky = k >> 2, ic = k & 3;
            int yin = y0 + r + ky - 3, cin = cc - 3;
            if (ic < 3 && yin >= 0 && yin < 32 && cin >= 0 && cin < 32) {
                size_t gi = (size_t)((b * 16 + t) * 3 + ic) * 1024 + yin * 32 + cin;
                v = fp32 ? ((const float*)xin)[gi]
                         : __bfloat162float(((const __hip_bfloat16*)xin)[gi]);
            }
        }
        __hip_bfloat16 hb = __float2bfloat16(v);
        lds[23040 + (r * 40 + cc) * 40 + k] = *(short*)&hb;
    }
    __syncthreads();

    // acc init: kg=0 carries the bias, kg=1 starts at zero (partials)
    f32x4 acc[4][4];
    if (kg == 0) {
        const float* bp = bias_r + dir * 256 + wm * 16 + q * 4;
#pragma unroll
        for (int g = 0; g < 4; ++g) {
            f32x4 bv = *(const f32x4*)(bp + g * 64);
#pragma unroll
            for (int nt = 0; nt < 4; ++nt) acc[g][nt] = bv;
        }
    } else {
        f32x4 z = {0.0f, 0.0f, 0.0f, 0.0f};
#pragma unroll
        for (int g = 0; g < 4; ++g)
#pragma unroll
            for (int nt = 0; nt < 4; ++nt) acc[g][nt] = z;
    }

    // lane bases
    const short* wbase = wall + (size_t)dir * 860160 + ((wm * 16 + li) * 32 + q * 8);
    int bh[4], bx[4];
#pragma unroll
    for (int nt = 0; nt < 4; ++nt) {
        int rt = nt >> 1, ct = nt & 1;
        bh[nt] = (rt * 40 + ct * 16 + li) * 72 + q * 8;
        bx[nt] = 23040 + (rt * 40 + ct * 16 + li) * 40 + q * 8;
    }

    auto loadA = [&](short8* A, int ks) {
        const short* p = wbase + (size_t)ks * 8192;
#pragma unroll
        for (int g = 0; g < 4; ++g) A[g] = *(const short8*)(p + g * 2048);
    };
    auto loadB = [&](short8* B, int ks) {
        if (ks < 98) {
            int ky = ks / 14, rr = ks % 14;
            int uoff = ky * 2880 + (rr % 7) * 72 + (rr / 7) * 32;
#pragma unroll
            for (int nt = 0; nt < 4; ++nt) B[nt] = *(const short8*)&lds[bh[nt] + uoff];
        } else {
            int uoff = (ks - 98) * 40;
#pragma unroll
            for (int nt = 0; nt < 4; ++nt) B[nt] = *(const short8*)&lds[bx[nt] + uoff];
        }
    };
    auto mfma16 = [&](short8* A, short8* B) {
        __builtin_amdgcn_s_setprio(1);      // T5
#pragma unroll
        for (int g = 0; g < 4; ++g)
#pragma unroll
            for (int nt = 0; nt < 4; ++nt)
                acc[g][nt] = __builtin_amdgcn_mfma_f32_16x16x32_bf16(A[g], B[nt], acc[g][nt], 0, 0, 0);
        __builtin_amdgcn_s_setprio(0);
    };

    // K-loop ranges: s==0 -> h==0 exactly, only x-conv ks [98,105) needed.
    const int ks_begin = (s == 0) ? (kg ? 101 : 98) : (kg ? 52 : 0);
    const int ks_end   = (s == 0) ? (kg ? 105 : 101) : (kg ? 105 : 52);
    short8 A0[4], A1[4], B0[4], B1[4];
    loadA(A0, ks_begin); loadB(B0, ks_begin);
    int ks = ks_begin;
#pragma unroll 1
    for (; ks + 1 < ks_end; ks += 2) {
        loadA(A1, ks + 1); loadB(B1, ks + 1);
        mfma16(A0, B0);
        int kn = (ks + 2 < ks_end) ? ks + 2 : ks; // clamp (redundant reload on last iter)
        loadA(A0, kn); loadB(B0, kn);
        mfma16(A1, B1);
    }
    if (ks < ks_end) mfma16(A0, B0); // odd-count tail

    // ---- combine partials: single-shot (64 KB exchange region) -----------
    // Fully unrolled, CONSTANT acc indices only (rule #20).
    __syncthreads();           // all waves done with h-tile/XB reads
    {
        float* exch = (float*)lds;
        float* xp = exch + wm * 4096 + q * 64 + li * 4;
        if (kg == 1) {
#pragma unroll
            for (int g = 0; g < 4; ++g)
#pragma unroll
                for (int nt = 0; nt < 4; ++nt)
                    *(f32x4*)(xp + (g * 4 + nt) * 256) = acc[g][nt];
        }
        __syncthreads();
        if (kg == 0) {
#pragma unroll
            for (int g = 0; g < 4; ++g)
#pragma unroll
                for (int nt = 0; nt < 4; ++nt)
                    acc[g][nt] += *(const f32x4*)(xp + (g * 4 + nt) * 256);
        }
    }
    if (kg == 1) return;       // no barriers past this point

    // epilogue (kg=0 only; all 4 gates present in-wave)
    const int hid0 = wm * 16 + q * 4;
#pragma unroll
    for (int nt = 0; nt < 4; ++nt) {
        int y = y0 + (nt >> 1);
        int px = (nt & 1) * 16 + li;
        float* cp = c + (size_t)(db * 1024 + y * 32 + px) * 64 + hid0;
        f32x4 cold;
        if (s == 0) {          // c == 0 at s=0: skip the cold read (bit-exact)
            cold = (f32x4){0.0f, 0.0f, 0.0f, 0.0f};
        } else {
            cold = *(const f32x4*)cp;
        }
        f32x4 hv;
#pragma unroll
        for (int r = 0; r < 4; ++r) {
            float iv = sigm(acc[0][nt][r]);
            float fv = sigm(acc[1][nt][r]);
            float gv = tanh_f(acc[2][nt][r]);
            float ov = sigm(acc[3][nt][r]);
            float cn = fv * cold[r] + iv * gv;
            cold[r] = cn;
            hv[r] = ov * tanh_f(cn);
        }
        *(f32x4*)cp = cold;

        ushort4 hu;
        {
            __hip_bfloat16 t0 = __float2bfloat16(hv[0]); hu.x = *(unsigned short*)&t0;
            __hip_bfloat16 t1 = __float2bfloat16(hv[1]); hu.y = *(unsigned short*)&t1;
            __hip_bfloat16 t2 = __float2bfloat16(hv[2]); hu.z = *(unsigned short*)&t2;
            __hip_bfloat16 t3 = __float2bfloat16(hv[3]); hu.w = *(unsigned short*)&t3;
        }
        *(ushort4*)(hp_w + (size_t)((db * 38 + y + 3) * 40 + px + 3) * 64 + hid0) = hu;

        size_t ob = (size_t)((b * 16 + t) * 128 + dir * 64 + hid0) * 1024 + y * 32 + px;
        if (fp32) {
            float* op = (float*)out;
#pragma unroll
            for (int r = 0; r < 4; ++r) op[ob + (size_t)r * 1024] = hv[r];
        } else {
            __hip_bfloat16* op = (__hip_bfloat16*)out;
#pragma unroll
            for (int r = 0; r < 4; ++r) op[ob + (size_t)r * 1024] = __float2bfloat16(hv[r]);
        }
    }
}

// ---- FALLBACK: R13-verified static-LDS kernel verbatim (592.4 us) --------
__global__ __launch_bounds__(512, 2)
void lstm_step_fb(const void* __restrict__ xin,
                  const short* __restrict__ wall,
                  const float* __restrict__ bias_r,
                  const unsigned short* __restrict__ hp_r,
                  unsigned short* __restrict__ hp_w,
                  float* __restrict__ c,
                  void* __restrict__ out,
                  const int* __restrict__ flag, int s) {
    const int bid = blockIdx.x;
    const int dir = bid & 1;
    const int b = (bid >> 1) & 7;
    const int ygrp = bid >> 4;
    const int t = dir ? (15 - s) : s;
    const int y0 = ygrp * 2;
    const int tid = threadIdx.x;
    const int wv = tid >> 6;
    const int kg = wv >> 2;
    const int wm = wv & 3;
    const int l = tid & 63;
    const int q = l >> 4;
    const int li = l & 15;
    const int fp32 = *flag;
    const int db = dir * 8 + b;

    __shared__ __align__(16) short lds[26240];

    if (s != 0) {
        const uint4* src = (const uint4*)(hp_r + (size_t)(db * 38 + y0) * 40 * 64);
        for (int i = tid; i < 2560; i += 512) {
            int ic8 = i & 7, col = (i >> 3) % 40, row = i / 320;
            uint4 v = src[i];
            *(uint4*)&lds[(row * 40 + col) * 72 + ic8 * 8] = v;
        }
    }
    for (int i = tid; i < 3200; i += 512) {
        int cc = i % 40;
        int r  = (i / 40) & 1;
        int k  = i / 80;
        float v = 0.0f;
        if (k < 28) {
            int ky = k >> 2, ic = k & 3;
            int yin = y0 + r + ky - 3, cin = cc - 3;
            if (ic < 3 && yin >= 0 && yin < 32 && cin >= 0 && cin < 32) {
                size_t gi = (size_t)((b * 16 + t) * 3 + ic) * 1024 + yin * 32 + cin;
                v = fp32 ? ((const float*)xin)[gi]
                         : __bfloat162float(((const __hip_bfloat16*)xin)[gi]);
            }
        }
        __hip_bfloat16 hb = __float2bfloat16(v);
        lds[23040 + (r * 40 + cc) * 40 + k] = *(short*)&hb;
    }
    __syncthreads();

    f32x4 acc[4][4];
    if (kg == 0) {
        const float* bp = bias_r + dir * 256 + wm * 16 + q * 4;
#pragma unroll
        for (int g = 0; g < 4; ++g) {
            f32x4 bv = *(const f32x4*)(bp + g * 64);
#pragma unroll
            for (int nt = 0; nt < 4; ++nt) acc[g][nt] = bv;
        }
    } else {
        f32x4 z = {0.0f, 0.0f, 0.0f, 0.0f};
#pragma unroll
        for (int g = 0; g < 4; ++g)
#pragma unroll
            for (int nt = 0; nt < 4; ++nt) acc[g][nt] = z;
    }

    const short* wbase = wall + (size_t)dir * 860160 + ((wm * 16 + li) * 32 + q * 8);
    int bh[4], bx[4];
#pragma unroll
    for (int nt = 0; nt < 4; ++nt) {
        int rt = nt >> 1, ct = nt & 1;
        bh[nt] = (rt * 40 + ct * 16 + li) * 72 + q * 8;
        bx[nt] = 23040 + (rt * 40 + ct * 16 + li) * 40 + q * 8;
    }

    auto loadA = [&](short8* A, int ks) {
        const short* p = wbase + (size_t)ks * 8192;
#pragma unroll
        for (int g = 0; g < 4; ++g) A[g] = *(const short8*)(p + g * 2048);
    };
    auto loadB = [&](short8* B, int ks) {
        if (ks < 98) {
            int ky = ks / 14, rr = ks % 14;
            int uoff = ky * 2880 + (rr % 7) * 72 + (rr / 7) * 32;
#pragma unroll
            for (int nt = 0; nt < 4; ++nt) B[nt] = *(const short8*)&lds[bh[nt] + uoff];
        } else {
            int uoff = (ks - 98) * 40;
#pragma unroll
            for (int nt = 0; nt < 4; ++nt) B[nt] = *(const short8*)&lds[bx[nt] + uoff];
        }
    };
    auto mfma16 = [&](short8* A, short8* B) {
        __builtin_amdgcn_s_setprio(1);
#pragma unroll
        for (int g = 0; g < 4; ++g)
#pragma unroll
            for (int nt = 0; nt < 4; ++nt)
                acc[g][nt] = __builtin_amdgcn_mfma_f32_16x16x32_bf16(A[g], B[nt], acc[g][nt], 0, 0, 0);
        __builtin_amdgcn_s_setprio(0);
    };

    const int ks_begin = (s == 0) ? (kg ? 101 : 98) : (kg ? 52 : 0);
    const int ks_end   = (s == 0) ? (kg ? 105 : 101) : (kg ? 105 : 52);
    short8 A0[4], A1[4], B0[4], B1[4];
    loadA(A0, ks_begin); loadB(B0, ks_begin);
    int ks = ks_begin;
#pragma unroll 1
    for (; ks + 1 < ks_end; ks += 2) {
        loadA(A1, ks + 1); loadB(B1, ks + 1);
        mfma16(A0, B0);
        int kn = (ks + 2 < ks_end) ? ks + 2 : ks;
        loadA(A0, kn); loadB(B0, kn);
        mfma16(A1, B1);
    }
    if (ks < ks_end) mfma16(A0, B0);

    __syncthreads();
    {
        float* exch = (float*)lds;
        float* xp = exch + wm * 2048 + q * 64 + li * 4;
        if (kg == 1) {
#pragma unroll
            for (int g = 0; g < 2; ++g)
#pragma unroll
                for (int nt = 0; nt < 4; ++nt)
                    *(f32x4*)(xp + (g * 4 + nt) * 256) = acc[g][nt];
        }
        __syncthreads();
        if (kg == 0) {
#pragma unroll
            for (int g = 0; g < 2; ++g)
#pragma unroll
                for (int nt = 0; nt < 4; ++nt)
                    acc[g][nt] += *(const f32x4*)(xp + (g * 4 + nt) * 256);
        }
        __syncthreads();
        if (kg == 1) {
#pragma unroll
            for (int g = 0; g < 2; ++g)
#pragma unroll
                for (int nt = 0; nt < 4; ++nt)
                    *(f32x4*)(xp + (g * 4 + nt) * 256) = acc[2 + g][nt];
        }
        __syncthreads();
        if (kg == 0) {
#pragma unroll
            for (int g = 0; g < 2; ++g)
#pragma unroll
                for (int nt = 0; nt < 4; ++nt)
                    acc[2 + g][nt] += *(const f32x4*)(xp + (g * 4 + nt) * 256);
        }
    }
    if (kg == 1) return;

    const int hid0 = wm * 16 + q * 4;
#pragma unroll
    for (int nt = 0; nt < 4; ++nt) {
        int y = y0 + (nt >> 1);
        int px = (nt & 1) * 16 + li;
        float* cp = c + (size_t)(db * 1024 + y * 32 + px) * 64 + hid0;
        f32x4 cold = *(const f32x4*)cp;
        f32x4 hv;
#pragma unroll
        for (int r = 0; r < 4; ++r) {
            float iv = sigm(acc[0][nt][r]);
            float fv = sigm(acc[1][nt][r]);
            float gv = tanh_f(acc[2][nt][r]);
            float ov = sigm(acc[3][nt][r]);
            float cn = fv * cold[r] + iv * gv;
            cold[r] = cn;
            hv[r] = ov * tanh_f(cn);
        }
        *(f32x4*)cp = cold;

        ushort4 hu;
        {
            __hip_bfloat16 t0 = __float2bfloat16(hv[0]); hu.x = *(unsigned short*)&t0;
            __hip_bfloat16 t1 = __float2bfloat16(hv[1]); hu.y = *(unsigned short*)&t1;
            __hip_bfloat16 t2 = __float2bfloat16(hv[2]); hu.z = *(unsigned short*)&t2;
            __hip_bfloat16 t3 = __float2bfloat16(hv[3]); hu.w = *(unsigned short*)&t3;
        }
        *(ushort4*)(hp_w + (size_t)((db * 38 + y + 3) * 40 + px + 3) * 64 + hid0) = hu;

        size_t ob = (size_t)((b * 16 + t) * 128 + dir * 64 + hid0) * 1024 + y * 32 + px;
        if (fp32) {
            float* op = (float*)out;
#pragma unroll
            for (int r = 0; r < 4; ++r) op[ob + (size_t)r * 1024] = hv[r];
        } else {
            __hip_bfloat16* op = (__hip_bfloat16*)out;
#pragma unroll
            for (int r = 0; r < 4; ++r) op[ob + (size_t)r * 1024] = __float2bfloat16(hv[r]);
        }
    }
}

extern "C" void kernel_launch(void* const* d_in, const int* in_sizes, int n_in,
                              void* d_out, int out_size, void* d_ws, size_t ws_size,
                              hipStream_t stream) {
    char* wsb = (char*)d_ws;
    unsigned short* hp0 = (unsigned short*)(wsb + HP0_B);
    unsigned short* hp1 = (unsigned short*)(wsb + HP1_B);
    float* c = (float*)(wsb + C_B);
    short* wall = (short*)(wsb + WALL_B);
    float* bias_r = (float*)(wsb + BIAS_B);
    int* flag = (int*)(wsb + FLAG_B);

    static int big_lds_ok = -1;
    if (big_lds_ok < 0) {
        hipError_t e = hipFuncSetAttribute((const void*)lstm_step,
                                           hipFuncAttributeMaxDynamicSharedMemorySize,
                                           65536);
        big_lds_ok = (e == hipSuccess) ? 1 : 0;
    }

    // inputs: 0=x 1=w_ih_f 2=w_hh_f 3=b_f 4=w_ih_b 5=w_hh_b 6=b_b
    hipMemsetAsync(d_ws, 0, 10420224, stream);   // hp0+hp1+c (capture-safe)
    detect_dtype<<<1, 64, 0, stream>>>((const unsigned int*)d_in[0], flag);
    prep_weights<<<6722, 256, 0, stream>>>(d_in[2], d_in[5], d_in[1], d_in[4],
                                           d_in[3], d_in[6], wall, bias_r, flag);

    if (big_lds_ok) {
        for (int s = 0; s < 16; ++s) {
            unsigned short* hr = (s & 1) ? hp1 : hp0;
            unsigned short* hw = (s & 1) ? hp0 : hp1;
            lstm_step<<<dim3(256), 512, 65536, stream>>>(d_in[0], wall, bias_r,
                                                         hr, hw, c, d_out, flag, s);
        }
    } else {
        for (int s = 0; s < 16; ++s) {
            unsigned short* hr = (s & 1) ? hp1 : hp0;
            unsigned short* hw = (s & 1) ? hp0 : hp1;
            lstm_step_fb<<<dim3(256), 512, 0, stream>>>(d_in[0], wall, bias_r,
                                                        hr, hw, c, d_out, flag, s);
        }
    }
}